// Round 1
// baseline (179.157 us; speedup 1.0000x reference)
//
#include <hip/hip_runtime.h>
#include <hip/hip_bf16.h>

typedef __bf16 bf16x4 __attribute__((ext_vector_type(4)));
typedef __bf16 bf16x8 __attribute__((ext_vector_type(8)));
typedef float  f32x4  __attribute__((ext_vector_type(4)));

#define BM 128
#define BN 128
#define BK 64
#define LDST 72   // LDS row stride in bf16 elems (BK + 8 pad -> 2-way max bank aliasing)

#define M_DIM 16384
#define N_DIM 512
#define K_DIM 512

__global__ __launch_bounds__(256, 2)
void snn_fused_kernel(const float* __restrict__ x, const float* __restrict__ W,
                      const float* __restrict__ gNa_p, const float* __restrict__ gK_p,
                      const float* __restrict__ gL_p, float* __restrict__ out)
{
    __shared__ __bf16 sA[BM * LDST];
    __shared__ __bf16 sB[BN * LDST];

    const int tid = threadIdx.x;
    const int bM  = blockIdx.y;   // 0..127
    const int bN  = blockIdx.x;   // 0..3

    // ---- staging indices: 256 threads, each thread does 8 rows x 4 floats per tile
    const int c4 = (tid & 15) * 4;   // k offset (floats)
    const int r0 = tid >> 4;         // 0..15, rows r0, r0+16, ..., r0+112

    const float* xBase = x + (long)(bM * BM + r0) * K_DIM + c4;
    const float* wBase = W + (long)(bN * BN + r0) * K_DIM + c4;

    // ---- wave / fragment indices
    const int wave = tid >> 6;        // 0..3
    const int lane = tid & 63;
    const int wM   = (wave & 1) * 64;
    const int wN   = (wave >> 1) * 64;
    const int lr   = lane & 15;       // m/n index within 16
    const int quad = lane >> 4;       // 0..3 -> k = quad*8 + j

    f32x4 acc[4][4] = {};

    for (int kt = 0; kt < K_DIM; kt += BK) {
        const float* xp = xBase + kt;
        const float* wp = wBase + kt;
        #pragma unroll
        for (int rr = 0; rr < 8; ++rr) {
            const int row = r0 + rr * 16;
            float4 va = *(const float4*)(xp + (long)rr * 16 * K_DIM);
            float4 vb = *(const float4*)(wp + (long)rr * 16 * K_DIM);
            bf16x4 ba = { (__bf16)va.x, (__bf16)va.y, (__bf16)va.z, (__bf16)va.w };
            bf16x4 bb = { (__bf16)vb.x, (__bf16)vb.y, (__bf16)vb.z, (__bf16)vb.w };
            *(bf16x4*)(&sA[row * LDST + c4]) = ba;
            *(bf16x4*)(&sB[row * LDST + c4]) = bb;
        }
        __syncthreads();

        #pragma unroll
        for (int ks = 0; ks < BK; ks += 32) {
            bf16x8 af[4], bfr[4];
            #pragma unroll
            for (int t = 0; t < 4; ++t) {
                af[t]  = *(const bf16x8*)(&sA[(wM + t * 16 + lr) * LDST + ks + quad * 8]);
                bfr[t] = *(const bf16x8*)(&sB[(wN + t * 16 + lr) * LDST + ks + quad * 8]);
            }
            #pragma unroll
            for (int mt = 0; mt < 4; ++mt)
                #pragma unroll
                for (int nt = 0; nt < 4; ++nt)
                    acc[mt][nt] = __builtin_amdgcn_mfma_f32_16x16x32_bf16(
                        af[mt], bfr[nt], acc[mt][nt], 0, 0, 0);
        }
        __syncthreads();
    }

    // ---- fused Hodgkin-Huxley epilogue ----
    const float gNa = *gNa_p, gK = *gK_p, gL = *gL_p;
    float* outS = out;
    float* outV = out + (long)M_DIM * N_DIM;
    float* outW = out + 2L * M_DIM * N_DIM;

    #pragma unroll
    for (int mt = 0; mt < 4; ++mt) {
        #pragma unroll
        for (int i = 0; i < 4; ++i) {
            const long gm = (long)bM * BM + wM + mt * 16 + quad * 4 + i;
            #pragma unroll
            for (int nt = 0; nt < 4; ++nt) {
                const int gn = bN * BN + wN + nt * 16 + lr;
                const float V = acc[mt][nt][i];

                const float vp40 = V + 40.0f;
                const float vp55 = V + 55.0f;
                const float vp65 = V + 65.0f;
                const float am = 0.1f * vp40 / (1.0f - __expf(-vp40 * 0.1f));
                const float bm = 4.0f * __expf(-vp65 * (1.0f / 18.0f));
                const float ah = 0.07f * __expf(-vp65 * 0.05f);
                const float bh = 1.0f / (1.0f + __expf(-(V + 35.0f) * 0.1f));
                const float an = 0.01f * vp55 / (1.0f - __expf(-vp55 * 0.1f));
                const float bn = 0.125f * __expf(-vp65 * 0.0125f);

                const float m = 0.05f + 0.1f * (am * 0.95f - bm * 0.05f);
                const float h = 0.60f + 0.1f * (ah * 0.40f - bh * 0.60f);
                const float n = 0.32f + 0.1f * (an * 0.68f - bn * 0.32f);

                const float m3 = m * m * m;
                const float n2 = n * n;
                const float n4 = n2 * n2;

                const float I_ion = gNa * m3 * h * (V - 50.0f)
                                  + gK * n4 * (V + 77.0f)
                                  + gL * (V + 54.4f);
                const float I_in  = I_ion + V;          // psp == V
                const float v_new = -65.0f + I_in * 0.005f;   // dt/tau_m
                const float spike = (v_new >= -50.0f) ? 1.0f : 0.0f;
                const float w_new = (0.5f * (v_new + 65.0f) + 0.1f * spike) * 0.001f;
                const float v_rs  = (spike > 0.5f) ? -65.0f : v_new;

                const long idx = gm * N_DIM + gn;
                outS[idx] = spike;
                outV[idx] = v_rs;
                outW[idx] = w_new;
            }
        }
    }
}

extern "C" void kernel_launch(void* const* d_in, const int* in_sizes, int n_in,
                              void* d_out, int out_size, void* d_ws, size_t ws_size,
                              hipStream_t stream) {
    const float* x   = (const float*)d_in[0];
    const float* W   = (const float*)d_in[1];
    const float* gNa = (const float*)d_in[2];
    const float* gK  = (const float*)d_in[3];
    const float* gL  = (const float*)d_in[4];
    float* out = (float*)d_out;

    dim3 grid(N_DIM / BN, M_DIM / BM);  // (4, 128)
    dim3 block(256);
    hipLaunchKernelGGL(snn_fused_kernel, grid, block, 0, stream, x, W, gNa, gK, gL, out);
}

// Round 2
// 156.661 us; speedup vs baseline: 1.1436x; 1.1436x over previous
//
#include <hip/hip_runtime.h>
#include <hip/hip_bf16.h>

typedef __bf16 bf16x4 __attribute__((ext_vector_type(4)));
typedef __bf16 bf16x8 __attribute__((ext_vector_type(8)));
typedef float  f32x4  __attribute__((ext_vector_type(4)));

#define BM 128
#define BN 128
#define BK 64
#define LDST 72   // LDS row stride in bf16 elems (BK + 8 pad)

#define M_DIM 16384
#define N_DIM 512
#define K_DIM 512

__global__ __launch_bounds__(256, 2)
void snn_fused_kernel(const float* __restrict__ x, const float* __restrict__ W,
                      const float* __restrict__ gNa_p, const float* __restrict__ gK_p,
                      const float* __restrict__ gL_p, float* __restrict__ out)
{
    __shared__ __bf16 sA[BM * LDST];
    __shared__ __bf16 sB[BN * LDST];

    const int tid = threadIdx.x;

    // XCD-aware swizzle: consecutive linear block ids round-robin XCDs.
    // Give each XCD a contiguous band of 16 bM tiles (4 MB of x = its L2)
    // with all 4 bN tiles resident -> x fetched from HBM once per byte.
    const int id   = blockIdx.x;           // 0..511
    const int xcd  = id & 7;
    const int slot = id >> 3;              // 0..63
    const int bm   = xcd * 16 + (slot >> 2);   // 0..127
    const int bn   = slot & 3;                 // 0..3

    // ---- staging indices: 256 threads, each thread does 8 rows x 4 floats per tile
    const int c4 = (tid & 15) * 4;   // k offset (floats)
    const int r0 = tid >> 4;         // 0..15; rows r0 + 16*rr

    const float* xBase = x + (long)(bm * BM + r0) * K_DIM + c4;
    const float* wBase = W + (long)(bn * BN + r0) * K_DIM + c4;

    // ---- wave / fragment indices
    const int wave = tid >> 6;        // 0..3
    const int lane = tid & 63;
    const int wM   = (wave & 1) * 64;
    const int wN   = (wave >> 1) * 64;
    const int lr   = lane & 15;       // m/n index within 16
    const int quad = lane >> 4;       // 0..3 -> k = quad*8 + j

    f32x4 acc[4][4] = {};

    // ---- software-pipelined staging: next tile prefetched into registers
    float4 pa[8], pb[8];
    #pragma unroll
    for (int rr = 0; rr < 8; ++rr) {
        pa[rr] = *(const float4*)(xBase + (long)rr * 16 * K_DIM);
        pb[rr] = *(const float4*)(wBase + (long)rr * 16 * K_DIM);
    }

    for (int kt = 0; kt < K_DIM; kt += BK) {
        // convert prefetched regs -> LDS (compiler inserts the vmcnt wait here)
        #pragma unroll
        for (int rr = 0; rr < 8; ++rr) {
            const int row = r0 + rr * 16;
            float4 va = pa[rr];
            float4 vb = pb[rr];
            bf16x4 ba = { (__bf16)va.x, (__bf16)va.y, (__bf16)va.z, (__bf16)va.w };
            bf16x4 bb = { (__bf16)vb.x, (__bf16)vb.y, (__bf16)vb.z, (__bf16)vb.w };
            *(bf16x4*)(&sA[row * LDST + c4]) = ba;
            *(bf16x4*)(&sB[row * LDST + c4]) = bb;
        }

        // issue next tile's 16 loads NOW -> in flight across barrier + MFMA
        if (kt + BK < K_DIM) {
            const float* xp = xBase + kt + BK;
            const float* wp = wBase + kt + BK;
            #pragma unroll
            for (int rr = 0; rr < 8; ++rr) {
                pa[rr] = *(const float4*)(xp + (long)rr * 16 * K_DIM);
                pb[rr] = *(const float4*)(wp + (long)rr * 16 * K_DIM);
            }
        }
        __syncthreads();

        #pragma unroll
        for (int ks = 0; ks < BK; ks += 32) {
            bf16x8 af[4], bfr[4];
            #pragma unroll
            for (int t = 0; t < 4; ++t) {
                af[t]  = *(const bf16x8*)(&sA[(wM + t * 16 + lr) * LDST + ks + quad * 8]);
                bfr[t] = *(const bf16x8*)(&sB[(wN + t * 16 + lr) * LDST + ks + quad * 8]);
            }
            #pragma unroll
            for (int mt = 0; mt < 4; ++mt)
                #pragma unroll
                for (int nt = 0; nt < 4; ++nt)
                    acc[mt][nt] = __builtin_amdgcn_mfma_f32_16x16x32_bf16(
                        af[mt], bfr[nt], acc[mt][nt], 0, 0, 0);
        }
        __syncthreads();
    }

    // ---- fused Hodgkin-Huxley epilogue ----
    const float gNa = *gNa_p, gK = *gK_p, gL = *gL_p;
    float* outS = out;
    float* outV = out + (long)M_DIM * N_DIM;
    float* outW = out + 2L * M_DIM * N_DIM;

    #pragma unroll
    for (int mt = 0; mt < 4; ++mt) {
        #pragma unroll
        for (int i = 0; i < 4; ++i) {
            const long gm = (long)bm * BM + wM + mt * 16 + quad * 4 + i;
            #pragma unroll
            for (int nt = 0; nt < 4; ++nt) {
                const int gn = bn * BN + wN + nt * 16 + lr;
                const float V = acc[mt][nt][i];

                const float vp40 = V + 40.0f;
                const float vp55 = V + 55.0f;
                const float vp65 = V + 65.0f;
                const float am = 0.1f * vp40 / (1.0f - __expf(-vp40 * 0.1f));
                const float bm_ = 4.0f * __expf(-vp65 * (1.0f / 18.0f));
                const float ah = 0.07f * __expf(-vp65 * 0.05f);
                const float bh = 1.0f / (1.0f + __expf(-(V + 35.0f) * 0.1f));
                const float an = 0.01f * vp55 / (1.0f - __expf(-vp55 * 0.1f));
                const float bn_ = 0.125f * __expf(-vp65 * 0.0125f);

                const float m = 0.05f + 0.1f * (am * 0.95f - bm_ * 0.05f);
                const float h = 0.60f + 0.1f * (ah * 0.40f - bh * 0.60f);
                const float n = 0.32f + 0.1f * (an * 0.68f - bn_ * 0.32f);

                const float m3 = m * m * m;
                const float n2 = n * n;
                const float n4 = n2 * n2;

                const float I_ion = gNa * m3 * h * (V - 50.0f)
                                  + gK * n4 * (V + 77.0f)
                                  + gL * (V + 54.4f);
                const float I_in  = I_ion + V;          // psp == V
                const float v_new = -65.0f + I_in * 0.005f;   // dt/tau_m
                const float spike = (v_new >= -50.0f) ? 1.0f : 0.0f;
                const float w_new = (0.5f * (v_new + 65.0f) + 0.1f * spike) * 0.001f;
                const float v_rs  = (spike > 0.5f) ? -65.0f : v_new;

                const long idx = gm * N_DIM + gn;
                outS[idx] = spike;
                outV[idx] = v_rs;
                outW[idx] = w_new;
            }
        }
    }
}

extern "C" void kernel_launch(void* const* d_in, const int* in_sizes, int n_in,
                              void* d_out, int out_size, void* d_ws, size_t ws_size,
                              hipStream_t stream) {
    const float* x   = (const float*)d_in[0];
    const float* W   = (const float*)d_in[1];
    const float* gNa = (const float*)d_in[2];
    const float* gK  = (const float*)d_in[3];
    const float* gL  = (const float*)d_in[4];
    float* out = (float*)d_out;

    dim3 grid((M_DIM / BM) * (N_DIM / BN));  // 512 blocks, 1-D for swizzle
    dim3 block(256);
    hipLaunchKernelGGL(snn_fused_kernel, grid, block, 0, stream, x, W, gNa, gK, gL, out);
}